// Round 9
// baseline (168.017 us; speedup 1.0000x reference)
//
#include <hip/hip_runtime.h>
#include <hip/hip_bf16.h>
#include <hip/hip_fp16.h>

// GIN via linearity: agg(x)@W == agg(x@W). Per layer: z = X@W (MFMA fp16,
// fp32 accum), then h = relu(z + gather_sum(z) + b) via on-device CSR.
// CSR: single-pass fixed-capacity coarse buckets (dst>>8, CAP slots each),
// packed 4B staging (src:16 | dst&255:16), LDS-local per-bucket finalize.
// r12: best structure (167.2us). r13: mega-kernel REGRESSED (occupancy).
// r14: neutral (GEMM1 split; kept). r15: gather ILP restructure (-5.6us,
//      161.8 BEST): unconditional clamped loads, select-predication.
// r16: REGRESSED (+2.7us): full row double-buffer pipeline -> ~+48 VGPR on
//      the 512-thr kernel traded TLP for ILP at a loss.
// r17: middle ground: keep ONLY the low-register half of r16 -- all 16
//      col-index loads hoisted into one upfront batch (+16 VGPR); rows
//      loaded per node (short-lived rr[4]/sr, no cross-node live ranges).
//      Serial trips per wave: 8 (r15) -> 5. gather_pool unchanged.

#define N_FEAT 64
#define CHUNK 4096
#define CAP 6144   // slots per coarse bucket (mean fill 4096, >30 sigma slack)

typedef _Float16 f16;
typedef _Float16 half8 __attribute__((ext_vector_type(8)));
typedef float float4v __attribute__((ext_vector_type(4)));
typedef unsigned short u16;

__device__ inline f16 cvt_f16(float v) { return (f16)v; }
__device__ inline f16 cvt_f16(f16 v) { return v; }

// ---- GEMM body via MFMA: 64 rows/block, 4 waves; wave w = 16-row strip ----
// smem: needs 2*64*72*2 = 18432 bytes
template <typename TIN>
__device__ __forceinline__ void gemm_body(const TIN* __restrict__ X, const float* __restrict__ W,
                                          f16* __restrict__ Z, int nrows, int bidx, char* smemc) {
    f16 (*sX)[72] = (f16 (*)[72])smemc;
    f16 (*sWT)[72] = (f16 (*)[72])(smemc + 64 * 72 * sizeof(f16));
    int t = threadIdx.x;
    int base = bidx * 64;
    for (int idx = t; idx < 4096; idx += 256) {
        int k = idx >> 6, n = idx & 63;
        sWT[n][k] = (f16)W[idx];               // W[k][n] -> sWT[n][k]
    }
    for (int idx = t; idx < 4096; idx += 256) {
        int r = idx >> 6, c = idx & 63;
        int row = base + r;
        sX[r][c] = (row < nrows) ? cvt_f16(X[(size_t)row * 64 + c]) : (f16)0.f;
    }
    __syncthreads();
    int wave = t >> 6;
    int lane = t & 63;
    int quad = lane >> 4;
    int m16 = lane & 15;
    half8 a0 = *(const half8*)&sX[wave * 16 + m16][quad * 8];
    half8 a1 = *(const half8*)&sX[wave * 16 + m16][32 + quad * 8];
    float4v acc[4];
#pragma unroll
    for (int C = 0; C < 4; ++C) {
        half8 b0 = *(const half8*)&sWT[C * 16 + m16][quad * 8];
        half8 b1 = *(const half8*)&sWT[C * 16 + m16][32 + quad * 8];
        float4v d = {0.f, 0.f, 0.f, 0.f};
        d = __builtin_amdgcn_mfma_f32_16x16x32_f16(a0, b0, d, 0, 0, 0);
        d = __builtin_amdgcn_mfma_f32_16x16x32_f16(a1, b1, d, 0, 0, 0);
        acc[C] = d;
    }
#pragma unroll
    for (int reg = 0; reg < 4; ++reg) {
        int row = base + wave * 16 + quad * 4 + reg;
        if (row < nrows) {
#pragma unroll
            for (int C = 0; C < 4; ++C)
                Z[(size_t)row * 64 + C * 16 + m16] = (f16)acc[C][reg];
        }
    }
}

// ---- CSR pass A body: coarse-bucket packed edges into fixed-capacity regions
// pack = src(16b) | (dst&255)<<16    (requires N <= 65536)
// smem: (CHUNK*2 + 512) * 4 = 34816 bytes
__device__ __forceinline__ void scatter_body(const int* __restrict__ src, const int* __restrict__ dst,
                                             int* __restrict__ ccur, int* __restrict__ staging,
                                             int E, int bidx, char* smemc) {
    int* epack = (int*)smemc;        // CHUNK
    int* ebkt  = epack + CHUNK;      // CHUNK
    int* hist  = ebkt + CHUNK;       // 256
    int* base  = hist + 256;         // 256
    int t = threadIdx.x;
    int begin = bidx * CHUNK;
    int cnt = min(CHUNK, E - begin);
    hist[t] = 0;
    __syncthreads();
    for (int i = t; i < cnt; i += 256) {
        int d = dst[begin + i];
        int s = src[begin + i];
        epack[i] = (s & 0xFFFF) | ((d & 255) << 16);
        ebkt[i] = d >> 8;
        atomicAdd(&hist[d >> 8], 1);
    }
    __syncthreads();
    int h = hist[t];
    if (h > 0) base[t] = atomicAdd(&ccur[t], h);
    hist[t] = 0;
    __syncthreads();
    for (int i = t; i < cnt; i += 256) {
        int b = ebkt[i];
        int off = base[b] + atomicAdd(&hist[b], 1);
        if (off < CAP) staging[(size_t)b * CAP + off] = epack[i];
    }
}

// ---- CSR pass B body: per-bucket hist+scan+scatter fully in LDS ----
// smem: needs (CAP + 768) * 4 = 27648 bytes
__device__ __forceinline__ void finalize_body(const int* __restrict__ staging, const int* __restrict__ ccur,
                                              int2* __restrict__ rowse, u16* __restrict__ col, int N,
                                              int b, char* smemc) {
    int* edges = (int*)smemc;          // CAP
    int* hist = edges + CAP;           // 256
    int* scan = hist + 256;            // 256
    int* cur = scan + 256;             // 256
    int t = threadIdx.x;
    int cnt = min(ccur[b], CAP);
    int sbase = b * CAP;
    hist[t] = 0;
    __syncthreads();
    for (int i = t; i < cnt; i += 256) {
        int e = staging[(size_t)sbase + i];
        edges[i] = e;
        atomicAdd(&hist[(e >> 16) & 255], 1);
    }
    __syncthreads();
    int v = hist[t];
    scan[t] = v;
    __syncthreads();
    for (int off = 1; off < 256; off <<= 1) {
        int u = (t >= off) ? scan[t - off] : 0;
        __syncthreads();
        scan[t] += u;
        __syncthreads();
    }
    int excl = scan[t] - v;
    cur[t] = excl;
    int node = b * 256 + t;
    if (node < N) rowse[node] = make_int2(sbase + excl, sbase + excl + v);
    __syncthreads();
    for (int i = t; i < cnt; i += 256) {
        int e = edges[i];
        int pos = sbase + atomicAdd(&cur[(e >> 16) & 255], 1);
        col[pos] = (u16)(e & 0xFFFF);
    }
}

// ---- dispatch A: scatter (blocks 0..nsb-1) || GEMM1 rows [0, g1a) ----
__global__ __launch_bounds__(256) void fused_scatter_gemm(
        const int* __restrict__ src, const int* __restrict__ dst,
        int* __restrict__ ccur, int* __restrict__ staging, int E,
        const float* __restrict__ X, const float* __restrict__ W,
        f16* __restrict__ Z, int nrows, int nsb) {
    __shared__ __align__(16) char smem[(CHUNK * 2 + 512) * 4];
    if ((int)blockIdx.x < nsb)
        scatter_body(src, dst, ccur, staging, E, blockIdx.x, smem);
    else
        gemm_body<float>(X, W, Z, nrows, blockIdx.x - nsb, smem);
}

// ---- dispatch B: finalize || GEMM1 rows [g1a, ...) || sums zeroing ----
__global__ __launch_bounds__(256) void fused_finalize_gemm(
        const int* __restrict__ staging, const int* __restrict__ ccur,
        int2* __restrict__ rowse, u16* __restrict__ col, int N,
        const float* __restrict__ X, const float* __restrict__ W,
        f16* __restrict__ Z, int nrows, int nbf, int g1a, int ng1b,
        float* __restrict__ sums, int sumsN) {
    __shared__ __align__(16) char smem[(CAP + 768) * 4];
    int b = blockIdx.x;
    if (b < nbf) {
        finalize_body(staging, ccur, rowse, col, N, b, smem);
    } else if (b < nbf + ng1b) {
        gemm_body<float>(X, W, Z, nrows, (b - nbf) + g1a, smem);
    } else {
        int zb = b - nbf - ng1b;
        float4* s4 = (float4*)sums;
        int n4 = sumsN >> 2;
        for (int i = zb * 256 + threadIdx.x; i < n4; i += 8 * 256)
            s4[i] = make_float4(0.f, 0.f, 0.f, 0.f);
    }
}

// ---- per-wave gather core (used by gather_pool): loads unconditional,
// predicate on accumulate via select (never mask-multiply: 0*NaN=NaN).
__device__ __forceinline__ void gather_core(const float4v* __restrict__ Z4,
                                            const u16* __restrict__ col,
                                            int lo, int hi, int e, int c, float* acc) {
    bool vv[4];
    int jj[4];
#pragma unroll
    for (int i = 0; i < 4; ++i) {
        int j = lo + e + i * 8;
        vv[i] = j < hi;
        jj[i] = vv[i] ? j : lo;            // cndmask, always in-bounds
    }
    int idx4[4];
#pragma unroll
    for (int i = 0; i < 4; ++i) idx4[i] = (int)col[jj[i]];   // 4 loads in flight
    float4v rr[4];
#pragma unroll
    for (int i = 0; i < 4; ++i) rr[i] = Z4[(size_t)idx4[i] * 8 + c]; // 4 in flight
#pragma unroll
    for (int i = 0; i < 4; ++i) {
        half8 hv = *(half8*)&rr[i];
#pragma unroll
        for (int k = 0; k < 8; ++k) {
            float t = vv[i] ? (float)hv[k] : 0.f;   // select, not multiply
            acc[k] += t;
        }
    }
    for (int j = lo + 32 + e; j < hi; j += 8) {   // rare tail (deg > 32)
        float4v r = Z4[(size_t)(int)col[j] * 8 + c];
        half8 hv = *(half8*)&r;
#pragma unroll
        for (int k = 0; k < 8; ++k) acc[k] += (float)hv[k];
    }
#pragma unroll
    for (int k = 0; k < 8; ++k) {
        acc[k] += __shfl_xor(acc[k], 8);
        acc[k] += __shfl_xor(acc[k], 16);
        acc[k] += __shfl_xor(acc[k], 32);
    }
}

// ---- fused gather1 + relu + layer-2 GEMM ----
// 512 threads = 8 waves; block owns 32 nodes (wave w -> nodes w*4..w*4+3).
// All 16 col-idx loads hoisted into ONE upfront batch (depend only on the
// 4 preloaded rowse); rows loaded per node (short-lived rr[4]/sr).
// Serial memory-trip depth per wave: 1 (cols) + 4 (rows) = 5.
__global__ __launch_bounds__(512) void gather_gemm(
        const f16* __restrict__ Z, const int2* __restrict__ rowse,
        const u16* __restrict__ col, const float* __restrict__ bias,
        const float* __restrict__ W2, f16* __restrict__ Z2, int n) {
    __shared__ f16 sH[32][72];
    __shared__ f16 sWT[64][72];
    int t = threadIdx.x;
    for (int idx = t; idx < 4096; idx += 512) {
        int k = idx >> 6, nn = idx & 63;
        sWT[nn][k] = (f16)W2[idx];             // W2[k][n] -> sWT[n][k]
    }
    int w = t >> 6;
    int lane = t & 63;
    int e = lane >> 3, c = lane & 7;
    int base = blockIdx.x * 32;
    const float4v* Z4 = reinterpret_cast<const float4v*>(Z);
    const float4* B4 = reinterpret_cast<const float4*>(bias);

    // preload all 4 rowse (clamped -> unconditional, all in flight)
    int2 se[4];
#pragma unroll
    for (int q = 0; q < 4; ++q) {
        int node = base + w * 4 + q;
        se[q] = rowse[node < n ? node : (n - 1)];
    }
    // all 16 col-index loads in ONE batch
    bool vv[4][4];
    int idxA[4][4];
#pragma unroll
    for (int q = 0; q < 4; ++q) {
#pragma unroll
        for (int i = 0; i < 4; ++i) {
            int j = se[q].x + e + i * 8;
            vv[q][i] = j < se[q].y;
            int jj = vv[q][i] ? j : se[q].x;
            idxA[q][i] = (int)col[jj];
        }
    }
#pragma unroll
    for (int q = 0; q < 4; ++q) {
        int node = base + w * 4 + q;
        bool valid = node < n;
        float4v sr = Z4[(size_t)(valid ? node : (n - 1)) * 8 + c];  // early
        float4v rr[4];
#pragma unroll
        for (int i = 0; i < 4; ++i) rr[i] = Z4[(size_t)idxA[q][i] * 8 + c];
        float acc[8] = {0.f, 0.f, 0.f, 0.f, 0.f, 0.f, 0.f, 0.f};
#pragma unroll
        for (int i = 0; i < 4; ++i) {
            half8 hv = *(half8*)&rr[i];
#pragma unroll
            for (int k = 0; k < 8; ++k)
                acc[k] += vv[q][i] ? (float)hv[k] : 0.f;   // select, not mul
        }
        for (int j = se[q].x + 32 + e; j < se[q].y; j += 8) {  // rare tail
            float4v r = Z4[(size_t)(int)col[j] * 8 + c];
            half8 hv = *(half8*)&r;
#pragma unroll
            for (int k = 0; k < 8; ++k) acc[k] += (float)hv[k];
        }
#pragma unroll
        for (int k = 0; k < 8; ++k) {
            acc[k] += __shfl_xor(acc[k], 8);
            acc[k] += __shfl_xor(acc[k], 16);
            acc[k] += __shfl_xor(acc[k], 32);
        }
        if (e == 0) {                          // lane == c here
            half8 o;
            if (valid) {
                half8 sv = *(half8*)&sr;
                float4 b0 = B4[c * 2];
                float4 b1 = B4[c * 2 + 1];
                float bb[8] = {b0.x, b0.y, b0.z, b0.w, b1.x, b1.y, b1.z, b1.w};
#pragma unroll
                for (int k = 0; k < 8; ++k)
                    o[k] = (f16)fmaxf((float)sv[k] + acc[k] + bb[k], 0.f);
            } else {
#pragma unroll
                for (int k = 0; k < 8; ++k) o[k] = (f16)0.f;
            }
            *(half8*)&sH[w * 4 + q][c * 8] = o;
        }
    }
    __syncthreads();
    // ---- 32x64 MFMA: wave w -> output tile (mrow = (w>>2)*16, ncol = (w&3)*16)
    int quad = lane >> 4;
    int m16 = lane & 15;
    int mrow = (w >> 2) * 16;
    int ncol = (w & 3) * 16;
    half8 a0 = *(const half8*)&sH[mrow + m16][quad * 8];
    half8 a1 = *(const half8*)&sH[mrow + m16][32 + quad * 8];
    half8 b0 = *(const half8*)&sWT[ncol + m16][quad * 8];
    half8 b1 = *(const half8*)&sWT[ncol + m16][32 + quad * 8];
    float4v d = {0.f, 0.f, 0.f, 0.f};
    d = __builtin_amdgcn_mfma_f32_16x16x32_f16(a0, b0, d, 0, 0, 0);
    d = __builtin_amdgcn_mfma_f32_16x16x32_f16(a1, b1, d, 0, 0, 0);
#pragma unroll
    for (int reg = 0; reg < 4; ++reg) {
        int row = base + mrow + quad * 4 + reg;
        if (row < n)
            Z2[(size_t)row * 64 + ncol + m16] = (f16)d[reg];
    }
}

// ---- gather2 + bias + relu + pool; 1 wave/node ----
// Block-local LDS combine of the 4 waves' h rows, atomicAdd per distinct
// graph (batch sorted -> usually one graph per block -> ~64 atomics/block).
__global__ __launch_bounds__(256) void gather_pool(
        const f16* __restrict__ Z, const int2* __restrict__ rowse,
        const u16* __restrict__ col, const float* __restrict__ bias,
        float* __restrict__ sums, const int* __restrict__ batch, int n) {
    __shared__ float sh[4][64];
    __shared__ int gid[4];
    int w = threadIdx.x >> 6;
    int node = (int)(blockIdx.x * 4 + w);
    int lane = threadIdx.x & 63;
    int e = lane >> 3, c = lane & 7;
    bool valid = node < n;
    int nodeC = valid ? node : (n - 1);
    int2 se = rowse[nodeC];                       // unconditional, early
    const float4v* Z4 = reinterpret_cast<const float4v*>(Z);
    float4v sr = Z4[(size_t)nodeC * 8 + c];       // self row, issued early
    float acc[8] = {0.f, 0.f, 0.f, 0.f, 0.f, 0.f, 0.f, 0.f};
    gather_core(Z4, col, se.x, se.y, e, c, acc);
    if (lane == 0) gid[w] = valid ? batch[node] : -1;
    if (valid && e == 0) {
        half8 sv = *(half8*)&sr;
        const float4* B4 = reinterpret_cast<const float4*>(bias);
        float4 b0 = B4[c * 2];
        float4 b1 = B4[c * 2 + 1];
        float bb[8] = {b0.x, b0.y, b0.z, b0.w, b1.x, b1.y, b1.z, b1.w};
#pragma unroll
        for (int k = 0; k < 8; ++k)
            sh[w][c * 8 + k] = fmaxf((float)sv[k] + acc[k] + bb[k], 0.f);
    }
    __syncthreads();
    if (w == 0) {
        int cg = gid[0];
        float run = 0.f;
#pragma unroll
        for (int q = 0; q < 4; ++q) {
            int g = gid[q];
            if (g < 0) break;
            if (g != cg) {
                atomicAdd(&sums[cg * 64 + lane], run);
                run = 0.f;
                cg = g;
            }
            run += sh[q][lane];
        }
        if (cg >= 0) atomicAdd(&sums[cg * 64 + lane], run);
    }
}

// ---- tiny head: out[g] = (sums[g]/cnt[g]) @ W3 + b3 ----
__global__ __launch_bounds__(64) void head_kernel(
        const float* __restrict__ sums, const int* __restrict__ batch,
        const float* __restrict__ W3, const float* __restrict__ b3,
        float* __restrict__ out, int n, int ncls) {
    int g = blockIdx.x;
    __shared__ float row[64];
    __shared__ int bnd[2];
    int t = threadIdx.x;
    if (t < 2) {
        int target = g + t;
        int lo = 0, hi = n;
        while (lo < hi) { int m = (lo + hi) >> 1; if (batch[m] < target) lo = m + 1; else hi = m; }
        bnd[t] = lo;
    }
    __syncthreads();
    float cnt = fmaxf((float)(bnd[1] - bnd[0]), 1.0f);
    row[t] = sums[g * 64 + t] / cnt;
    __syncthreads();
    if (t < ncls) {
        float o = b3[t];
#pragma unroll
        for (int k = 0; k < 64; ++k) o += row[k] * W3[k * ncls + t];
        out[g * ncls + t] = o;
    }
}

extern "C" void kernel_launch(void* const* d_in, const int* in_sizes, int n_in,
                              void* d_out, int out_size, void* d_ws, size_t ws_size,
                              hipStream_t stream) {
    const float* x     = (const float*)d_in[0];
    const int*   ei    = (const int*)d_in[1];   // [2, E]
    const int*   batch = (const int*)d_in[2];
    const float* W1    = (const float*)d_in[3];
    const float* b1    = (const float*)d_in[4];
    const float* W2    = (const float*)d_in[5];
    const float* b2    = (const float*)d_in[6];
    const float* W3    = (const float*)d_in[7];
    const float* b3    = (const float*)d_in[8];
    float* out = (float*)d_out;

    const int N = in_sizes[0] / N_FEAT;       // 50000
    const int E = in_sizes[1] / 2;            // 800000
    const int NCLS = 10;
    const int G = out_size / NCLS;            // 500
    const int* src = ei;
    const int* dst = ei + E;
    const int nb = (N + 255) / 256;           // 196 coarse buckets

    // workspace layout (all offsets kept 16B-aligned)
    int*   staging = (int*)d_ws;                              // nb*CAP packed
    int2*  rowse   = (int2*)(staging + (size_t)nb * CAP);     // N
    u16*   col     = (u16*)(rowse + N);                       // nb*CAP (2B each)
    size_t colInts = ((size_t)nb * CAP * 2 + 15) / 16 * 4;    // in ints, 16B pad
    int*   ccur    = (int*)(rowse + N) + colInts;             // 256
    float* sums    = (float*)(ccur + 256);                    // G*64 (pool acc)
    f16*   zbuf    = (f16*)(sums + (size_t)G * 64);           // N*64  (z1)
    f16*   z2buf   = zbuf + (size_t)N * 64;                   // N*64  (z2)

    const int gemmGrid = (N + 63) / 64;           // 782
    const int gg2Grid  = (N + 31) / 32;           // 1563
    const int gatherGrid = (N + 3) / 4;           // 12500
    const int scatGrid = (E + CHUNK - 1) / CHUNK; // 196
    const int g1a = 304;                          // GEMM1 blocks w/ scatter
    const int g1b = gemmGrid - g1a;               // GEMM1 blocks w/ finalize
    const int zblk = 8;                           // sums-zeroing blocks

    // ---- zero ccur only (sums zeroed inside dispatch B) ----
    hipMemsetAsync(ccur, 0, 256 * sizeof(int), stream);

    // ---- dispatch A: scatter || GEMM1[0, g1a) ----
    fused_scatter_gemm<<<scatGrid + g1a, 256, 0, stream>>>(
        src, dst, ccur, staging, E, x, W1, zbuf, N, scatGrid);

    // ---- dispatch B: finalize || GEMM1[g1a, ...) || zero sums ----
    fused_finalize_gemm<<<nb + g1b + zblk, 256, 0, stream>>>(
        staging, ccur, rowse, col, N, x, W1, zbuf, N, nb, g1a, g1b,
        sums, G * 64);

    // ---- layer-1 gather + relu + layer-2 GEMM (one dispatch) ----
    gather_gemm<<<gg2Grid, 512, 0, stream>>>(zbuf, rowse, col, b1, W2, z2buf, N);

    // ---- layer-2 gather + pool ----
    gather_pool<<<gatherGrid, 256, 0, stream>>>(z2buf, rowse, col, b2, sums, batch, N);

    // ---- head ----
    head_kernel<<<G, 64, 0, stream>>>(sums, batch, W3, b3, out, N, NCLS);
}

// Round 10
// 161.717 us; speedup vs baseline: 1.0390x; 1.0390x over previous
//
#include <hip/hip_runtime.h>
#include <hip/hip_bf16.h>
#include <hip/hip_fp16.h>

// GIN via linearity: agg(x)@W == agg(x@W). Per layer: z = X@W (MFMA fp16,
// fp32 accum), then h = relu(z + gather_sum(z) + b) via on-device CSR.
// CSR: single-pass fixed-capacity coarse buckets (dst>>8, CAP slots each),
// packed 4B staging (src:16 | dst&255:16), LDS-local per-bucket finalize.
// r12: best structure (167.2us). r13: mega-kernel REGRESSED (occupancy).
// r14: neutral (GEMM1 split; kept). r15: gather ILP restructure (-5.6us,
//      161.8 BEST): unconditional clamped loads, select-predication,
//      short per-node chains, minimal cross-node register state.
// r16: REGRESSED (+2.7): row double-buffer pipeline (+~48 VGPR, lost TLP).
// r17: REGRESSED (+6.2): col-hoist-only (+~20 VGPR live across node bodies).
// r18: FINAL = exact r15 source (best measured). Lesson: this kernel lives
//      on TLP; any register-funded ILP deepening in gather_gemm loses more
//      occupancy than it gains in pipeline depth. Remaining time is
//      latency/launch-bound; all further levers measured within +-3us noise.

#define N_FEAT 64
#define CHUNK 4096
#define CAP 6144   // slots per coarse bucket (mean fill 4096, >30 sigma slack)

typedef _Float16 f16;
typedef _Float16 half8 __attribute__((ext_vector_type(8)));
typedef float float4v __attribute__((ext_vector_type(4)));
typedef unsigned short u16;

__device__ inline f16 cvt_f16(float v) { return (f16)v; }
__device__ inline f16 cvt_f16(f16 v) { return v; }

// ---- GEMM body via MFMA: 64 rows/block, 4 waves; wave w = 16-row strip ----
// smem: needs 2*64*72*2 = 18432 bytes
template <typename TIN>
__device__ __forceinline__ void gemm_body(const TIN* __restrict__ X, const float* __restrict__ W,
                                          f16* __restrict__ Z, int nrows, int bidx, char* smemc) {
    f16 (*sX)[72] = (f16 (*)[72])smemc;
    f16 (*sWT)[72] = (f16 (*)[72])(smemc + 64 * 72 * sizeof(f16));
    int t = threadIdx.x;
    int base = bidx * 64;
    for (int idx = t; idx < 4096; idx += 256) {
        int k = idx >> 6, n = idx & 63;
        sWT[n][k] = (f16)W[idx];               // W[k][n] -> sWT[n][k]
    }
    for (int idx = t; idx < 4096; idx += 256) {
        int r = idx >> 6, c = idx & 63;
        int row = base + r;
        sX[r][c] = (row < nrows) ? cvt_f16(X[(size_t)row * 64 + c]) : (f16)0.f;
    }
    __syncthreads();
    int wave = t >> 6;
    int lane = t & 63;
    int quad = lane >> 4;
    int m16 = lane & 15;
    half8 a0 = *(const half8*)&sX[wave * 16 + m16][quad * 8];
    half8 a1 = *(const half8*)&sX[wave * 16 + m16][32 + quad * 8];
    float4v acc[4];
#pragma unroll
    for (int C = 0; C < 4; ++C) {
        half8 b0 = *(const half8*)&sWT[C * 16 + m16][quad * 8];
        half8 b1 = *(const half8*)&sWT[C * 16 + m16][32 + quad * 8];
        float4v d = {0.f, 0.f, 0.f, 0.f};
        d = __builtin_amdgcn_mfma_f32_16x16x32_f16(a0, b0, d, 0, 0, 0);
        d = __builtin_amdgcn_mfma_f32_16x16x32_f16(a1, b1, d, 0, 0, 0);
        acc[C] = d;
    }
#pragma unroll
    for (int reg = 0; reg < 4; ++reg) {
        int row = base + wave * 16 + quad * 4 + reg;
        if (row < nrows) {
#pragma unroll
            for (int C = 0; C < 4; ++C)
                Z[(size_t)row * 64 + C * 16 + m16] = (f16)acc[C][reg];
        }
    }
}

// ---- CSR pass A body: coarse-bucket packed edges into fixed-capacity regions
// pack = src(16b) | (dst&255)<<16    (requires N <= 65536)
// smem: (CHUNK*2 + 512) * 4 = 34816 bytes
__device__ __forceinline__ void scatter_body(const int* __restrict__ src, const int* __restrict__ dst,
                                             int* __restrict__ ccur, int* __restrict__ staging,
                                             int E, int bidx, char* smemc) {
    int* epack = (int*)smemc;        // CHUNK
    int* ebkt  = epack + CHUNK;      // CHUNK
    int* hist  = ebkt + CHUNK;       // 256
    int* base  = hist + 256;         // 256
    int t = threadIdx.x;
    int begin = bidx * CHUNK;
    int cnt = min(CHUNK, E - begin);
    hist[t] = 0;
    __syncthreads();
    for (int i = t; i < cnt; i += 256) {
        int d = dst[begin + i];
        int s = src[begin + i];
        epack[i] = (s & 0xFFFF) | ((d & 255) << 16);
        ebkt[i] = d >> 8;
        atomicAdd(&hist[d >> 8], 1);
    }
    __syncthreads();
    int h = hist[t];
    if (h > 0) base[t] = atomicAdd(&ccur[t], h);
    hist[t] = 0;
    __syncthreads();
    for (int i = t; i < cnt; i += 256) {
        int b = ebkt[i];
        int off = base[b] + atomicAdd(&hist[b], 1);
        if (off < CAP) staging[(size_t)b * CAP + off] = epack[i];
    }
}

// ---- CSR pass B body: per-bucket hist+scan+scatter fully in LDS ----
// smem: needs (CAP + 768) * 4 = 27648 bytes
__device__ __forceinline__ void finalize_body(const int* __restrict__ staging, const int* __restrict__ ccur,
                                              int2* __restrict__ rowse, u16* __restrict__ col, int N,
                                              int b, char* smemc) {
    int* edges = (int*)smemc;          // CAP
    int* hist = edges + CAP;           // 256
    int* scan = hist + 256;            // 256
    int* cur = scan + 256;             // 256
    int t = threadIdx.x;
    int cnt = min(ccur[b], CAP);
    int sbase = b * CAP;
    hist[t] = 0;
    __syncthreads();
    for (int i = t; i < cnt; i += 256) {
        int e = staging[(size_t)sbase + i];
        edges[i] = e;
        atomicAdd(&hist[(e >> 16) & 255], 1);
    }
    __syncthreads();
    int v = hist[t];
    scan[t] = v;
    __syncthreads();
    for (int off = 1; off < 256; off <<= 1) {
        int u = (t >= off) ? scan[t - off] : 0;
        __syncthreads();
        scan[t] += u;
        __syncthreads();
    }
    int excl = scan[t] - v;
    cur[t] = excl;
    int node = b * 256 + t;
    if (node < N) rowse[node] = make_int2(sbase + excl, sbase + excl + v);
    __syncthreads();
    for (int i = t; i < cnt; i += 256) {
        int e = edges[i];
        int pos = sbase + atomicAdd(&cur[(e >> 16) & 255], 1);
        col[pos] = (u16)(e & 0xFFFF);
    }
}

// ---- dispatch A: scatter (blocks 0..nsb-1) || GEMM1 rows [0, g1a) ----
__global__ __launch_bounds__(256) void fused_scatter_gemm(
        const int* __restrict__ src, const int* __restrict__ dst,
        int* __restrict__ ccur, int* __restrict__ staging, int E,
        const float* __restrict__ X, const float* __restrict__ W,
        f16* __restrict__ Z, int nrows, int nsb) {
    __shared__ __align__(16) char smem[(CHUNK * 2 + 512) * 4];
    if ((int)blockIdx.x < nsb)
        scatter_body(src, dst, ccur, staging, E, blockIdx.x, smem);
    else
        gemm_body<float>(X, W, Z, nrows, blockIdx.x - nsb, smem);
}

// ---- dispatch B: finalize || GEMM1 rows [g1a, ...) || sums zeroing ----
__global__ __launch_bounds__(256) void fused_finalize_gemm(
        const int* __restrict__ staging, const int* __restrict__ ccur,
        int2* __restrict__ rowse, u16* __restrict__ col, int N,
        const float* __restrict__ X, const float* __restrict__ W,
        f16* __restrict__ Z, int nrows, int nbf, int g1a, int ng1b,
        float* __restrict__ sums, int sumsN) {
    __shared__ __align__(16) char smem[(CAP + 768) * 4];
    int b = blockIdx.x;
    if (b < nbf) {
        finalize_body(staging, ccur, rowse, col, N, b, smem);
    } else if (b < nbf + ng1b) {
        gemm_body<float>(X, W, Z, nrows, (b - nbf) + g1a, smem);
    } else {
        int zb = b - nbf - ng1b;
        float4* s4 = (float4*)sums;
        int n4 = sumsN >> 2;
        for (int i = zb * 256 + threadIdx.x; i < n4; i += 8 * 256)
            s4[i] = make_float4(0.f, 0.f, 0.f, 0.f);
    }
}

// ---- per-wave gather core: ALL loads unconditional, predicate on accumulate.
// jj clamped to lo (always a valid col slot); garbage u16 indices land inside
// the 256MB workspace and are masked out by the select (never mask-multiply:
// poisoned memory may decode as NaN and 0*NaN = NaN).
__device__ __forceinline__ void gather_core(const float4v* __restrict__ Z4,
                                            const u16* __restrict__ col,
                                            int lo, int hi, int e, int c, float* acc) {
    bool vv[4];
    int jj[4];
#pragma unroll
    for (int i = 0; i < 4; ++i) {
        int j = lo + e + i * 8;
        vv[i] = j < hi;
        jj[i] = vv[i] ? j : lo;            // cndmask, always in-bounds
    }
    int idx4[4];
#pragma unroll
    for (int i = 0; i < 4; ++i) idx4[i] = (int)col[jj[i]];   // 4 loads in flight
    float4v rr[4];
#pragma unroll
    for (int i = 0; i < 4; ++i) rr[i] = Z4[(size_t)idx4[i] * 8 + c]; // 4 in flight
#pragma unroll
    for (int i = 0; i < 4; ++i) {
        half8 hv = *(half8*)&rr[i];
#pragma unroll
        for (int k = 0; k < 8; ++k) {
            float t = vv[i] ? (float)hv[k] : 0.f;   // select, not multiply
            acc[k] += t;
        }
    }
    for (int j = lo + 32 + e; j < hi; j += 8) {   // rare tail (deg > 32)
        float4v r = Z4[(size_t)(int)col[j] * 8 + c];
        half8 hv = *(half8*)&r;
#pragma unroll
        for (int k = 0; k < 8; ++k) acc[k] += (float)hv[k];
    }
#pragma unroll
    for (int k = 0; k < 8; ++k) {
        acc[k] += __shfl_xor(acc[k], 8);
        acc[k] += __shfl_xor(acc[k], 16);
        acc[k] += __shfl_xor(acc[k], 32);
    }
}

// ---- fused gather1 + relu + layer-2 GEMM ----
// 512 threads = 8 waves; block owns 32 nodes (wave w -> nodes w*4..w*4+3).
// Per node: 8 edge slots (e=lane>>3) x 8 chunks of 16B (c=lane&7); rowse for
// all 4 nodes preloaded (clamped), self-row issued before the gather batch.
__global__ __launch_bounds__(512) void gather_gemm(
        const f16* __restrict__ Z, const int2* __restrict__ rowse,
        const u16* __restrict__ col, const float* __restrict__ bias,
        const float* __restrict__ W2, f16* __restrict__ Z2, int n) {
    __shared__ f16 sH[32][72];
    __shared__ f16 sWT[64][72];
    int t = threadIdx.x;
    for (int idx = t; idx < 4096; idx += 512) {
        int k = idx >> 6, nn = idx & 63;
        sWT[nn][k] = (f16)W2[idx];             // W2[k][n] -> sWT[n][k]
    }
    int w = t >> 6;
    int lane = t & 63;
    int e = lane >> 3, c = lane & 7;
    int base = blockIdx.x * 32;
    const float4v* Z4 = reinterpret_cast<const float4v*>(Z);
    const float4* B4 = reinterpret_cast<const float4*>(bias);
    // preload all 4 rowse (clamped -> unconditional loads, all in flight)
    int2 se[4];
#pragma unroll
    for (int q = 0; q < 4; ++q) {
        int node = base + w * 4 + q;
        se[q] = rowse[node < n ? node : (n - 1)];
    }
#pragma unroll
    for (int q = 0; q < 4; ++q) {
        int node = base + w * 4 + q;
        bool valid = node < n;
        int nodeC = valid ? node : (n - 1);
        float4v sr = Z4[(size_t)nodeC * 8 + c];   // self row, issued early
        float acc[8] = {0.f, 0.f, 0.f, 0.f, 0.f, 0.f, 0.f, 0.f};
        gather_core(Z4, col, se[q].x, se[q].y, e, c, acc);
        if (e == 0) {                          // lane == c here
            half8 o;
            if (valid) {
                half8 sv = *(half8*)&sr;
                float4 b0 = B4[c * 2];
                float4 b1 = B4[c * 2 + 1];
                float bb[8] = {b0.x, b0.y, b0.z, b0.w, b1.x, b1.y, b1.z, b1.w};
#pragma unroll
                for (int k = 0; k < 8; ++k)
                    o[k] = (f16)fmaxf((float)sv[k] + acc[k] + bb[k], 0.f);
            } else {
#pragma unroll
                for (int k = 0; k < 8; ++k) o[k] = (f16)0.f;
            }
            *(half8*)&sH[w * 4 + q][c * 8] = o;
        }
    }
    __syncthreads();
    // ---- 32x64 MFMA: wave w -> output tile (mrow = (w>>2)*16, ncol = (w&3)*16)
    int quad = lane >> 4;
    int m16 = lane & 15;
    int mrow = (w >> 2) * 16;
    int ncol = (w & 3) * 16;
    half8 a0 = *(const half8*)&sH[mrow + m16][quad * 8];
    half8 a1 = *(const half8*)&sH[mrow + m16][32 + quad * 8];
    half8 b0 = *(const half8*)&sWT[ncol + m16][quad * 8];
    half8 b1 = *(const half8*)&sWT[ncol + m16][32 + quad * 8];
    float4v d = {0.f, 0.f, 0.f, 0.f};
    d = __builtin_amdgcn_mfma_f32_16x16x32_f16(a0, b0, d, 0, 0, 0);
    d = __builtin_amdgcn_mfma_f32_16x16x32_f16(a1, b1, d, 0, 0, 0);
#pragma unroll
    for (int reg = 0; reg < 4; ++reg) {
        int row = base + mrow + quad * 4 + reg;
        if (row < n)
            Z2[(size_t)row * 64 + ncol + m16] = (f16)d[reg];
    }
}

// ---- gather2 + bias + relu + pool; 1 wave/node ----
// Block-local LDS combine of the 4 waves' h rows, atomicAdd per distinct
// graph (batch sorted -> usually one graph per block -> ~64 atomics/block).
__global__ __launch_bounds__(256) void gather_pool(
        const f16* __restrict__ Z, const int2* __restrict__ rowse,
        const u16* __restrict__ col, const float* __restrict__ bias,
        float* __restrict__ sums, const int* __restrict__ batch, int n) {
    __shared__ float sh[4][64];
    __shared__ int gid[4];
    int w = threadIdx.x >> 6;
    int node = (int)(blockIdx.x * 4 + w);
    int lane = threadIdx.x & 63;
    int e = lane >> 3, c = lane & 7;
    bool valid = node < n;
    int nodeC = valid ? node : (n - 1);
    int2 se = rowse[nodeC];                       // unconditional, early
    const float4v* Z4 = reinterpret_cast<const float4v*>(Z);
    float4v sr = Z4[(size_t)nodeC * 8 + c];       // self row, issued early
    float acc[8] = {0.f, 0.f, 0.f, 0.f, 0.f, 0.f, 0.f, 0.f};
    gather_core(Z4, col, se.x, se.y, e, c, acc);
    if (lane == 0) gid[w] = valid ? batch[node] : -1;
    if (valid && e == 0) {
        half8 sv = *(half8*)&sr;
        const float4* B4 = reinterpret_cast<const float4*>(bias);
        float4 b0 = B4[c * 2];
        float4 b1 = B4[c * 2 + 1];
        float bb[8] = {b0.x, b0.y, b0.z, b0.w, b1.x, b1.y, b1.z, b1.w};
#pragma unroll
        for (int k = 0; k < 8; ++k)
            sh[w][c * 8 + k] = fmaxf((float)sv[k] + acc[k] + bb[k], 0.f);
    }
    __syncthreads();
    if (w == 0) {
        int cg = gid[0];
        float run = 0.f;
#pragma unroll
        for (int q = 0; q < 4; ++q) {
            int g = gid[q];
            if (g < 0) break;
            if (g != cg) {
                atomicAdd(&sums[cg * 64 + lane], run);
                run = 0.f;
                cg = g;
            }
            run += sh[q][lane];
        }
        if (cg >= 0) atomicAdd(&sums[cg * 64 + lane], run);
    }
}

// ---- tiny head: out[g] = (sums[g]/cnt[g]) @ W3 + b3 ----
__global__ __launch_bounds__(64) void head_kernel(
        const float* __restrict__ sums, const int* __restrict__ batch,
        const float* __restrict__ W3, const float* __restrict__ b3,
        float* __restrict__ out, int n, int ncls) {
    int g = blockIdx.x;
    __shared__ float row[64];
    __shared__ int bnd[2];
    int t = threadIdx.x;
    if (t < 2) {
        int target = g + t;
        int lo = 0, hi = n;
        while (lo < hi) { int m = (lo + hi) >> 1; if (batch[m] < target) lo = m + 1; else hi = m; }
        bnd[t] = lo;
    }
    __syncthreads();
    float cnt = fmaxf((float)(bnd[1] - bnd[0]), 1.0f);
    row[t] = sums[g * 64 + t] / cnt;
    __syncthreads();
    if (t < ncls) {
        float o = b3[t];
#pragma unroll
        for (int k = 0; k < 64; ++k) o += row[k] * W3[k * ncls + t];
        out[g * ncls + t] = o;
    }
}

extern "C" void kernel_launch(void* const* d_in, const int* in_sizes, int n_in,
                              void* d_out, int out_size, void* d_ws, size_t ws_size,
                              hipStream_t stream) {
    const float* x     = (const float*)d_in[0];
    const int*   ei    = (const int*)d_in[1];   // [2, E]
    const int*   batch = (const int*)d_in[2];
    const float* W1    = (const float*)d_in[3];
    const float* b1    = (const float*)d_in[4];
    const float* W2    = (const float*)d_in[5];
    const float* b2    = (const float*)d_in[6];
    const float* W3    = (const float*)d_in[7];
    const float* b3    = (const float*)d_in[8];
    float* out = (float*)d_out;

    const int N = in_sizes[0] / N_FEAT;       // 50000
    const int E = in_sizes[1] / 2;            // 800000
    const int NCLS = 10;
    const int G = out_size / NCLS;            // 500
    const int* src = ei;
    const int* dst = ei + E;
    const int nb = (N + 255) / 256;           // 196 coarse buckets

    // workspace layout (all offsets kept 16B-aligned)
    int*   staging = (int*)d_ws;                              // nb*CAP packed
    int2*  rowse   = (int2*)(staging + (size_t)nb * CAP);     // N
    u16*   col     = (u16*)(rowse + N);                       // nb*CAP (2B each)
    size_t colInts = ((size_t)nb * CAP * 2 + 15) / 16 * 4;    // in ints, 16B pad
    int*   ccur    = (int*)(rowse + N) + colInts;             // 256
    float* sums    = (float*)(ccur + 256);                    // G*64 (pool acc)
    f16*   zbuf    = (f16*)(sums + (size_t)G * 64);           // N*64  (z1)
    f16*   z2buf   = zbuf + (size_t)N * 64;                   // N*64  (z2)

    const int gemmGrid = (N + 63) / 64;           // 782
    const int gg2Grid  = (N + 31) / 32;           // 1563
    const int gatherGrid = (N + 3) / 4;           // 12500
    const int scatGrid = (E + CHUNK - 1) / CHUNK; // 196
    const int g1a = 304;                          // GEMM1 blocks w/ scatter
    const int g1b = gemmGrid - g1a;               // GEMM1 blocks w/ finalize
    const int zblk = 8;                           // sums-zeroing blocks

    // ---- zero ccur only (sums zeroed inside dispatch B) ----
    hipMemsetAsync(ccur, 0, 256 * sizeof(int), stream);

    // ---- dispatch A: scatter || GEMM1[0, g1a) ----
    fused_scatter_gemm<<<scatGrid + g1a, 256, 0, stream>>>(
        src, dst, ccur, staging, E, x, W1, zbuf, N, scatGrid);

    // ---- dispatch B: finalize || GEMM1[g1a, ...) || zero sums ----
    fused_finalize_gemm<<<nb + g1b + zblk, 256, 0, stream>>>(
        staging, ccur, rowse, col, N, x, W1, zbuf, N, nb, g1a, g1b,
        sums, G * 64);

    // ---- layer-1 gather + relu + layer-2 GEMM (one dispatch) ----
    gather_gemm<<<gg2Grid, 512, 0, stream>>>(zbuf, rowse, col, b1, W2, z2buf, N);

    // ---- layer-2 gather + pool ----
    gather_pool<<<gatherGrid, 256, 0, stream>>>(z2buf, rowse, col, b2, sums, batch, N);

    // ---- head ----
    head_kernel<<<G, 64, 0, stream>>>(sums, batch, W3, b3, out, N, NCLS);
}